// Round 8
// baseline (169.440 us; speedup 1.0000x reference)
//
#include <hip/hip_runtime.h>

#define SENSOR_W 640
#define SENSOR_H 480
#define HW_PIX (SENSOR_W * SENSOR_H)        // 307200 pixels (= bins per channel)
#define N_OUT (2 * HW_PIX)                  // 614400 output bins
#define NBLOCKS 256
#define NTHREADS 1024
#define EVT 64                              // events per thread (fully unrolled)
#define HIST_WORDS (HW_PIX / 8)             // 38400 words = 153,600 B nibble LDS
#define C_WORDS (N_OUT / 8)                 // 76800 packed output words

__device__ __forceinline__ unsigned make_key(float4 e) {
    int x = (int)e.x;                       // astype(int32) == trunc
    int y = (int)e.y;
    if (x >= 0 && x < SENSOR_W && y >= 0 && y < SENSOR_H) {
        unsigned ch = (e.w > 0.0f) ? 0u : 1u;    // pos -> ch0, neg -> ch1
        return ch * (unsigned)HW_PIX + (unsigned)y * SENSOR_W + (unsigned)x;
    }
    return 0xFFFFFFFFu;                     // out of both ranges
}

// One block per CU. Phase 1: single raw-event pass -> ch0 nibble histogram
// (the whole positive channel fits LDS) + keys kept in VGPRs (static index).
// Phase 2: ch1 histogram replayed FROM REGISTERS — events are read exactly
// once and no key buffer ever touches memory.
__global__ __launch_bounds__(NTHREADS)
void hist_twophase(const float4* __restrict__ events,
                   unsigned* __restrict__ priv) {
    __shared__ unsigned lds[HIST_WORDS];
    unsigned keys[EVT];

    for (int i = threadIdx.x; i < HIST_WORDS; i += NTHREADS) lds[i] = 0u;
    __syncthreads();

    const float4* base = events + (size_t)blockIdx.x * (EVT * NTHREADS);

    // Phase 1: ch0 (positive) histogram + key stash
    #pragma unroll
    for (int k = 0; k < EVT; ++k) {
        float4 e = base[k * NTHREADS + threadIdx.x];
        unsigned key = make_key(e);
        keys[k] = key;
        if (key < (unsigned)HW_PIX)
            atomicAdd(&lds[key >> 3], 1u << ((key & 7u) << 2));
    }
    __syncthreads();

    // Flush ch0 copy and re-zero. Each thread flushes exactly the words it
    // zeroes -> no cross-thread hazard, single barrier after the loop.
    unsigned* dst = priv + (size_t)blockIdx.x * (2 * HIST_WORDS);
    for (int i = threadIdx.x; i < HIST_WORDS; i += NTHREADS) {
        dst[i] = lds[i];
        lds[i] = 0u;
    }
    __syncthreads();

    // Phase 2: ch1 (negative) histogram from registers
    #pragma unroll
    for (int k = 0; k < EVT; ++k) {
        unsigned l = keys[k] - (unsigned)HW_PIX;   // ch1 local bin or huge
        if (l < (unsigned)HW_PIX)
            atomicAdd(&lds[l >> 3], 1u << ((l & 7u) << 2));
    }
    __syncthreads();

    for (int i = threadIdx.x; i < HIST_WORDS; i += NTHREADS)
        dst[HIST_WORDS + i] = lds[i];
}

// Sum 256 nibble copies per channel + base image -> float output.
// Byte-packed partial sums over 16-copy chunks (max 16*15 = 240 <= 255).
__global__ void reduce_all(const unsigned* __restrict__ priv,
                           const float4* __restrict__ base4,
                           float4* __restrict__ out4) {
    int w = blockIdx.x * blockDim.x + threadIdx.x;   // packed-word index
    if (w >= C_WORDS) return;
    int part = (w >= HIST_WORDS) ? 1 : 0;            // 0 = ch0 words, 1 = ch1
    int lw = w - part * HIST_WORDS;
    const unsigned* src = priv + (size_t)part * HIST_WORDS + lw;

    unsigned s0=0,s1=0,s2=0,s3=0,s4=0,s5=0,s6=0,s7=0;
    for (int c0 = 0; c0 < NBLOCKS; c0 += 16) {
        unsigned alo = 0, ahi = 0;
        #pragma unroll
        for (int c = 0; c < 16; ++c) {
            unsigned v = src[(size_t)(c0 + c) * (2 * HIST_WORDS)];
            alo += v & 0x0F0F0F0Fu;          // even nibbles -> bytes
            ahi += (v >> 4) & 0x0F0F0F0Fu;   // odd nibbles  -> bytes
        }
        s0 += alo & 0xFFu;  s2 += (alo >> 8) & 0xFFu;
        s4 += (alo >> 16) & 0xFFu;  s6 += alo >> 24;
        s1 += ahi & 0xFFu;  s3 += (ahi >> 8) & 0xFFu;
        s5 += (ahi >> 16) & 0xFFu;  s7 += ahi >> 24;
    }
    // word w covers global bins 8w..8w+7
    float4 b0 = base4[2 * w], b1 = base4[2 * w + 1];
    out4[2 * w]     = make_float4(b0.x + (float)s0, b0.y + (float)s1,
                                  b0.z + (float)s2, b0.w + (float)s3);
    out4[2 * w + 1] = make_float4(b1.x + (float)s4, b1.y + (float)s5,
                                  b1.z + (float)s6, b1.w + (float)s7);
}

// ---------- fallback (round-2 path: device atomics into d_out) ----------

__global__ void zero_kernel(unsigned* __restrict__ cnt, int n) {
    int i = blockIdx.x * blockDim.x + threadIdx.x;
    int stride = gridDim.x * blockDim.x;
    for (; i < n; i += stride) cnt[i] = 0u;
}

__global__ void event_scatter_fallback(const float4* __restrict__ events,
                                       unsigned* __restrict__ cnt, int n_events) {
    int i = blockIdx.x * blockDim.x + threadIdx.x;
    int stride = gridDim.x * blockDim.x;
    for (; i < n_events; i += stride) {
        float4 ev = events[i];
        int x = (int)ev.x, y = (int)ev.y;
        if (x >= 0 && x < SENSOR_W && y >= 0 && y < SENSOR_H) {
            int ch = (ev.w > 0.0f) ? 0 : 1;
            atomicAdd(&cnt[ch * HW_PIX + y * SENSOR_W + x], 1u);
        }
    }
}

__global__ void finalize_fallback(const float* __restrict__ event_image,
                                  float* __restrict__ out, int n) {
    int i = blockIdx.x * blockDim.x + threadIdx.x;
    int stride = gridDim.x * blockDim.x;
    for (; i < n; i += stride) {
        unsigned c = ((const unsigned*)out)[i];
        out[i] = event_image[i] + (float)c;
    }
}

extern "C" void kernel_launch(void* const* d_in, const int* in_sizes, int n_in,
                              void* d_out, int out_size, void* d_ws, size_t ws_size,
                              hipStream_t stream) {
    const float4* events = (const float4*)d_in[0];
    const float* event_image = (const float*)d_in[1];
    float* out = (float*)d_out;

    int n_events = in_sizes[0] / 4;                  // 16,777,216
    size_t priv_bytes = (size_t)NBLOCKS * 2 * HIST_WORDS * sizeof(unsigned); // 78.6 MB

    bool shape_ok = (n_events == NBLOCKS * NTHREADS * EVT);

    if (ws_size >= priv_bytes && shape_ok) {
        unsigned* priv = (unsigned*)d_ws;

        // 1) single-pass two-phase histogram (keys live in VGPRs)
        hist_twophase<<<NBLOCKS, NTHREADS, 0, stream>>>(events, priv);

        // 2) reduce 256 copies per channel + base -> out
        reduce_all<<<(C_WORDS + 255) / 256, 256, 0, stream>>>(
            priv, (const float4*)event_image, (float4*)out);
    } else {
        // fallback: round-2 path (known-correct)
        int n_out = out_size;
        zero_kernel<<<(n_out + 255) / 256, 256, 0, stream>>>((unsigned*)out, n_out);
        event_scatter_fallback<<<2048, 256, 0, stream>>>(events, (unsigned*)out, n_events);
        finalize_fallback<<<(n_out + 255) / 256, 256, 0, stream>>>(event_image, out, n_out);
    }
}

// Round 9
// 165.112 us; speedup vs baseline: 1.0262x; 1.0262x over previous
//
#include <hip/hip_runtime.h>

#define SENSOR_W 640
#define SENSOR_H 480
#define HW_PIX (SENSOR_W * SENSOR_H)        // 307200 pixels (= bins per channel)
#define N_OUT (2 * HW_PIX)                  // 614400 output bins
#define NBLOCKS 256
#define NTHREADS 1024
#define HIST_WORDS (HW_PIX / 8)             // 38400 words = 153,600 B nibble LDS
#define C_WORDS (N_OUT / 8)                 // 76800 packed output words

__device__ __forceinline__ unsigned make_key(float4 e) {
    int x = (int)e.x;                       // astype(int32) == trunc
    int y = (int)e.y;
    if (x >= 0 && x < SENSOR_W && y >= 0 && y < SENSOR_H) {
        unsigned ch = (e.w > 0.0f) ? 0u : 1u;    // pos -> ch0, neg -> ch1
        return ch * (unsigned)HW_PIX + (unsigned)y * SENSOR_W + (unsigned)x;
    }
    return 0xFFFFFFFFu;                     // in neither channel
}

// Kernel A: read raw events ONCE. ch0 (positive) nibble histogram in LDS
// (whole channel fits: 153.6 KB) + plain coalesced uint32 key store for B.
// No compaction machinery (round-7 lesson: it cost more than it saved).
__global__ __launch_bounds__(NTHREADS)
void hist_ch0_write_keys(const float4* __restrict__ events,
                         unsigned* __restrict__ priv0,
                         unsigned* __restrict__ keys, int per_slice) {
    __shared__ unsigned lds[HIST_WORDS];
    for (int i = threadIdx.x; i < HIST_WORDS; i += NTHREADS) lds[i] = 0u;
    __syncthreads();

    const float4* ev = events + (size_t)blockIdx.x * per_slice;
    unsigned* kb = keys + (size_t)blockIdx.x * per_slice;

    for (int i = threadIdx.x; i < per_slice; i += 4 * NTHREADS) {
        float4 e0 = ev[i];
        float4 e1 = ev[i + NTHREADS];
        float4 e2 = ev[i + 2 * NTHREADS];
        float4 e3 = ev[i + 3 * NTHREADS];
        unsigned k0 = make_key(e0), k1 = make_key(e1);
        unsigned k2 = make_key(e2), k3 = make_key(e3);
        kb[i] = k0;
        kb[i + NTHREADS] = k1;
        kb[i + 2 * NTHREADS] = k2;
        kb[i + 3 * NTHREADS] = k3;
        if (k0 < (unsigned)HW_PIX) atomicAdd(&lds[k0 >> 3], 1u << ((k0 & 7u) << 2));
        if (k1 < (unsigned)HW_PIX) atomicAdd(&lds[k1 >> 3], 1u << ((k1 & 7u) << 2));
        if (k2 < (unsigned)HW_PIX) atomicAdd(&lds[k2 >> 3], 1u << ((k2 & 7u) << 2));
        if (k3 < (unsigned)HW_PIX) atomicAdd(&lds[k3 >> 3], 1u << ((k3 & 7u) << 2));
    }
    __syncthreads();

    unsigned* dst = priv0 + (size_t)blockIdx.x * HIST_WORDS;
    for (int i = threadIdx.x; i < HIST_WORDS; i += NTHREADS) dst[i] = lds[i];
}

// Kernel B: ch1 (negative) nibble histogram from the 4B key stream
// (uint4-vectorized; block b re-reads the slice written by A's block b ->
// same XCD under round-robin dispatch, partially L2-hot).
__global__ __launch_bounds__(NTHREADS)
void hist_ch1_from_keys(const unsigned* __restrict__ keys,
                        unsigned* __restrict__ priv1, int per_slice) {
    __shared__ unsigned lds[HIST_WORDS];
    for (int i = threadIdx.x; i < HIST_WORDS; i += NTHREADS) lds[i] = 0u;
    __syncthreads();

    const uint4* kb = (const uint4*)(keys + (size_t)blockIdx.x * per_slice);
    int n4 = per_slice >> 2;

    for (int i = threadIdx.x; i < n4; i += NTHREADS) {
        uint4 k = kb[i];
        unsigned l;
        l = k.x - (unsigned)HW_PIX;
        if (l < (unsigned)HW_PIX) atomicAdd(&lds[l >> 3], 1u << ((l & 7u) << 2));
        l = k.y - (unsigned)HW_PIX;
        if (l < (unsigned)HW_PIX) atomicAdd(&lds[l >> 3], 1u << ((l & 7u) << 2));
        l = k.z - (unsigned)HW_PIX;
        if (l < (unsigned)HW_PIX) atomicAdd(&lds[l >> 3], 1u << ((l & 7u) << 2));
        l = k.w - (unsigned)HW_PIX;
        if (l < (unsigned)HW_PIX) atomicAdd(&lds[l >> 3], 1u << ((l & 7u) << 2));
    }
    __syncthreads();

    unsigned* dst = priv1 + (size_t)blockIdx.x * HIST_WORDS;
    for (int i = threadIdx.x; i < HIST_WORDS; i += NTHREADS) dst[i] = lds[i];
}

// Kernel C: sum 256 nibble copies per channel + base image -> float output.
// Byte-packed partial sums over 16-copy chunks (max 16*15 = 240 <= 255).
__global__ void reduce_all(const unsigned* __restrict__ priv0,
                           const unsigned* __restrict__ priv1,
                           const float4* __restrict__ base4,
                           float4* __restrict__ out4) {
    int w = blockIdx.x * blockDim.x + threadIdx.x;   // packed-word index
    if (w >= C_WORDS) return;
    const unsigned* src = (w < HIST_WORDS) ? (priv0 + w)
                                           : (priv1 + (w - HIST_WORDS));
    unsigned s0=0,s1=0,s2=0,s3=0,s4=0,s5=0,s6=0,s7=0;
    for (int c0 = 0; c0 < NBLOCKS; c0 += 16) {
        unsigned alo = 0, ahi = 0;
        #pragma unroll
        for (int c = 0; c < 16; ++c) {
            unsigned v = src[(size_t)(c0 + c) * HIST_WORDS];
            alo += v & 0x0F0F0F0Fu;          // even nibbles -> bytes
            ahi += (v >> 4) & 0x0F0F0F0Fu;   // odd nibbles  -> bytes
        }
        s0 += alo & 0xFFu;  s2 += (alo >> 8) & 0xFFu;
        s4 += (alo >> 16) & 0xFFu;  s6 += alo >> 24;
        s1 += ahi & 0xFFu;  s3 += (ahi >> 8) & 0xFFu;
        s5 += (ahi >> 16) & 0xFFu;  s7 += ahi >> 24;
    }
    float4 b0 = base4[2 * w], b1 = base4[2 * w + 1];
    out4[2 * w]     = make_float4(b0.x + (float)s0, b0.y + (float)s1,
                                  b0.z + (float)s2, b0.w + (float)s3);
    out4[2 * w + 1] = make_float4(b1.x + (float)s4, b1.y + (float)s5,
                                  b1.z + (float)s6, b1.w + (float)s7);
}

// ---------- fallback (round-2 path: device atomics into d_out) ----------

__global__ void zero_kernel(unsigned* __restrict__ cnt, int n) {
    int i = blockIdx.x * blockDim.x + threadIdx.x;
    int stride = gridDim.x * blockDim.x;
    for (; i < n; i += stride) cnt[i] = 0u;
}

__global__ void event_scatter_fallback(const float4* __restrict__ events,
                                       unsigned* __restrict__ cnt, int n_events) {
    int i = blockIdx.x * blockDim.x + threadIdx.x;
    int stride = gridDim.x * blockDim.x;
    for (; i < n_events; i += stride) {
        float4 ev = events[i];
        int x = (int)ev.x, y = (int)ev.y;
        if (x >= 0 && x < SENSOR_W && y >= 0 && y < SENSOR_H) {
            int ch = (ev.w > 0.0f) ? 0 : 1;
            atomicAdd(&cnt[ch * HW_PIX + y * SENSOR_W + x], 1u);
        }
    }
}

__global__ void finalize_fallback(const float* __restrict__ event_image,
                                  float* __restrict__ out, int n) {
    int i = blockIdx.x * blockDim.x + threadIdx.x;
    int stride = gridDim.x * blockDim.x;
    for (; i < n; i += stride) {
        unsigned c = ((const unsigned*)out)[i];
        out[i] = event_image[i] + (float)c;
    }
}

extern "C" void kernel_launch(void* const* d_in, const int* in_sizes, int n_in,
                              void* d_out, int out_size, void* d_ws, size_t ws_size,
                              hipStream_t stream) {
    const float4* events = (const float4*)d_in[0];
    const float* event_image = (const float*)d_in[1];
    float* out = (float*)d_out;

    int n_events = in_sizes[0] / 4;                  // 16,777,216
    int per_slice = n_events / NBLOCKS;              // 65536

    size_t keys_bytes = (size_t)n_events * sizeof(unsigned);               // 67.1 MB
    size_t priv_bytes = (size_t)NBLOCKS * HIST_WORDS * sizeof(unsigned);   // 39.3 MB each
    size_t need = keys_bytes + 2 * priv_bytes;                             // ~145.7 MB

    bool shape_ok = (n_events % NBLOCKS == 0) &&
                    (per_slice % (4 * NTHREADS) == 0);

    if (ws_size >= need && shape_ok) {
        unsigned* keys  = (unsigned*)d_ws;
        unsigned* priv0 = (unsigned*)((char*)d_ws + keys_bytes);
        unsigned* priv1 = (unsigned*)((char*)d_ws + keys_bytes + priv_bytes);

        // A: events read once -> ch0 hist + key stream
        hist_ch0_write_keys<<<NBLOCKS, NTHREADS, 0, stream>>>(
            events, priv0, keys, per_slice);

        // B: ch1 hist from 4B keys
        hist_ch1_from_keys<<<NBLOCKS, NTHREADS, 0, stream>>>(
            keys, priv1, per_slice);

        // C: reduce 2x256 copies + base -> out
        reduce_all<<<(C_WORDS + 255) / 256, 256, 0, stream>>>(
            priv0, priv1, (const float4*)event_image, (float4*)out);
    } else {
        // fallback: round-2 path (known-correct)
        int n_out = out_size;
        zero_kernel<<<(n_out + 255) / 256, 256, 0, stream>>>((unsigned*)out, n_out);
        event_scatter_fallback<<<2048, 256, 0, stream>>>(events, (unsigned*)out, n_events);
        finalize_fallback<<<(n_out + 255) / 256, 256, 0, stream>>>(event_image, out, n_out);
    }
}

// Round 10
// 162.095 us; speedup vs baseline: 1.0453x; 1.0186x over previous
//
#include <hip/hip_runtime.h>

#define SENSOR_W 640
#define SENSOR_H 480
#define HW_PIX (SENSOR_W * SENSOR_H)        // 307200 pixels (= bins per channel)
#define N_OUT (2 * HW_PIX)                  // 614400 output bins
#define NBLOCKS 256
#define NTHREADS 1024
#define HIST_WORDS (HW_PIX / 8)             // 38400 words = 153,600 B nibble LDS
#define C_WORDS (N_OUT / 8)                 // 76800 packed output words

__device__ __forceinline__ unsigned make_key(float4 e) {
    int x = (int)e.x;                       // astype(int32) == trunc
    int y = (int)e.y;
    if (x >= 0 && x < SENSOR_W && y >= 0 && y < SENSOR_H) {
        unsigned ch = (e.w > 0.0f) ? 0u : 1u;    // pos -> ch0, neg -> ch1
        return ch * (unsigned)HW_PIX + (unsigned)y * SENSOR_W + (unsigned)x;
    }
    return 0xFFFFFFFFu;                     // in neither channel
}

// Kernel A: read raw events ONCE (round-6's proven coalesced pattern).
// ch0 (positive) nibble histogram in LDS (whole channel fits: 153.6 KB) +
// keys written as ONE uint4 store per thread-iteration, in PERMUTED order
// (histograms are order-invariant, so no remap needed). Round-9 lesson:
// four scalar 4B stores per iteration throttled the whole stream.
__global__ __launch_bounds__(NTHREADS)
void hist_ch0_write_keys(const float4* __restrict__ events,
                         unsigned* __restrict__ priv0,
                         uint4* __restrict__ keys4, int per_slice) {
    __shared__ unsigned lds[HIST_WORDS];
    for (int i = threadIdx.x; i < HIST_WORDS; i += NTHREADS) lds[i] = 0u;
    __syncthreads();

    const float4* ev = events + (size_t)blockIdx.x * per_slice;
    uint4* kb = keys4 + (size_t)blockIdx.x * (per_slice / 4);
    int iters = per_slice / (4 * NTHREADS);          // 16

    for (int j = 0; j < iters; ++j) {
        int i = j * 4 * NTHREADS + threadIdx.x;
        float4 e0 = ev[i];
        float4 e1 = ev[i + NTHREADS];
        float4 e2 = ev[i + 2 * NTHREADS];
        float4 e3 = ev[i + 3 * NTHREADS];
        unsigned k0 = make_key(e0), k1 = make_key(e1);
        unsigned k2 = make_key(e2), k3 = make_key(e3);
        uint4 kk; kk.x = k0; kk.y = k1; kk.z = k2; kk.w = k3;
        kb[j * NTHREADS + threadIdx.x] = kk;         // 16B/lane coalesced
        if (k0 < (unsigned)HW_PIX) atomicAdd(&lds[k0 >> 3], 1u << ((k0 & 7u) << 2));
        if (k1 < (unsigned)HW_PIX) atomicAdd(&lds[k1 >> 3], 1u << ((k1 & 7u) << 2));
        if (k2 < (unsigned)HW_PIX) atomicAdd(&lds[k2 >> 3], 1u << ((k2 & 7u) << 2));
        if (k3 < (unsigned)HW_PIX) atomicAdd(&lds[k3 >> 3], 1u << ((k3 & 7u) << 2));
    }
    __syncthreads();

    unsigned* dst = priv0 + (size_t)blockIdx.x * HIST_WORDS;
    for (int i = threadIdx.x; i < HIST_WORDS; i += NTHREADS) dst[i] = lds[i];
}

// Kernel B: ch1 (negative) nibble histogram from the 4B key stream
// (uint4 coalesced reads; block b re-reads the slice A's block b wrote ->
// same XCD under round-robin dispatch, partially L2/L3-hot).
__global__ __launch_bounds__(NTHREADS)
void hist_ch1_from_keys(const uint4* __restrict__ keys4,
                        unsigned* __restrict__ priv1, int per_slice) {
    __shared__ unsigned lds[HIST_WORDS];
    for (int i = threadIdx.x; i < HIST_WORDS; i += NTHREADS) lds[i] = 0u;
    __syncthreads();

    const uint4* kb = keys4 + (size_t)blockIdx.x * (per_slice / 4);
    int n4 = per_slice / 4;

    for (int i = threadIdx.x; i < n4; i += NTHREADS) {
        uint4 k = kb[i];
        unsigned l;
        l = k.x - (unsigned)HW_PIX;
        if (l < (unsigned)HW_PIX) atomicAdd(&lds[l >> 3], 1u << ((l & 7u) << 2));
        l = k.y - (unsigned)HW_PIX;
        if (l < (unsigned)HW_PIX) atomicAdd(&lds[l >> 3], 1u << ((l & 7u) << 2));
        l = k.z - (unsigned)HW_PIX;
        if (l < (unsigned)HW_PIX) atomicAdd(&lds[l >> 3], 1u << ((l & 7u) << 2));
        l = k.w - (unsigned)HW_PIX;
        if (l < (unsigned)HW_PIX) atomicAdd(&lds[l >> 3], 1u << ((l & 7u) << 2));
    }
    __syncthreads();

    unsigned* dst = priv1 + (size_t)blockIdx.x * HIST_WORDS;
    for (int i = threadIdx.x; i < HIST_WORDS; i += NTHREADS) dst[i] = lds[i];
}

// Kernel C: sum 256 nibble copies per channel + base image -> float output.
// Byte-packed partial sums over 16-copy chunks (max 16*15 = 240 <= 255).
__global__ void reduce_all(const unsigned* __restrict__ priv0,
                           const unsigned* __restrict__ priv1,
                           const float4* __restrict__ base4,
                           float4* __restrict__ out4) {
    int w = blockIdx.x * blockDim.x + threadIdx.x;   // packed-word index
    if (w >= C_WORDS) return;
    const unsigned* src = (w < HIST_WORDS) ? (priv0 + w)
                                           : (priv1 + (w - HIST_WORDS));
    unsigned s0=0,s1=0,s2=0,s3=0,s4=0,s5=0,s6=0,s7=0;
    for (int c0 = 0; c0 < NBLOCKS; c0 += 16) {
        unsigned alo = 0, ahi = 0;
        #pragma unroll
        for (int c = 0; c < 16; ++c) {
            unsigned v = src[(size_t)(c0 + c) * HIST_WORDS];
            alo += v & 0x0F0F0F0Fu;          // even nibbles -> bytes
            ahi += (v >> 4) & 0x0F0F0F0Fu;   // odd nibbles  -> bytes
        }
        s0 += alo & 0xFFu;  s2 += (alo >> 8) & 0xFFu;
        s4 += (alo >> 16) & 0xFFu;  s6 += alo >> 24;
        s1 += ahi & 0xFFu;  s3 += (ahi >> 8) & 0xFFu;
        s5 += (ahi >> 16) & 0xFFu;  s7 += ahi >> 24;
    }
    float4 b0 = base4[2 * w], b1 = base4[2 * w + 1];
    out4[2 * w]     = make_float4(b0.x + (float)s0, b0.y + (float)s1,
                                  b0.z + (float)s2, b0.w + (float)s3);
    out4[2 * w + 1] = make_float4(b1.x + (float)s4, b1.y + (float)s5,
                                  b1.z + (float)s6, b1.w + (float)s7);
}

// ---------- fallback (round-2 path: device atomics into d_out) ----------

__global__ void zero_kernel(unsigned* __restrict__ cnt, int n) {
    int i = blockIdx.x * blockDim.x + threadIdx.x;
    int stride = gridDim.x * blockDim.x;
    for (; i < n; i += stride) cnt[i] = 0u;
}

__global__ void event_scatter_fallback(const float4* __restrict__ events,
                                       unsigned* __restrict__ cnt, int n_events) {
    int i = blockIdx.x * blockDim.x + threadIdx.x;
    int stride = gridDim.x * blockDim.x;
    for (; i < n_events; i += stride) {
        float4 ev = events[i];
        int x = (int)ev.x, y = (int)ev.y;
        if (x >= 0 && x < SENSOR_W && y >= 0 && y < SENSOR_H) {
            int ch = (ev.w > 0.0f) ? 0 : 1;
            atomicAdd(&cnt[ch * HW_PIX + y * SENSOR_W + x], 1u);
        }
    }
}

__global__ void finalize_fallback(const float* __restrict__ event_image,
                                  float* __restrict__ out, int n) {
    int i = blockIdx.x * blockDim.x + threadIdx.x;
    int stride = gridDim.x * blockDim.x;
    for (; i < n; i += stride) {
        unsigned c = ((const unsigned*)out)[i];
        out[i] = event_image[i] + (float)c;
    }
}

extern "C" void kernel_launch(void* const* d_in, const int* in_sizes, int n_in,
                              void* d_out, int out_size, void* d_ws, size_t ws_size,
                              hipStream_t stream) {
    const float4* events = (const float4*)d_in[0];
    const float* event_image = (const float*)d_in[1];
    float* out = (float*)d_out;

    int n_events = in_sizes[0] / 4;                  // 16,777,216
    int per_slice = n_events / NBLOCKS;              // 65536

    size_t keys_bytes = (size_t)n_events * sizeof(unsigned);               // 67.1 MB
    size_t priv_bytes = (size_t)NBLOCKS * HIST_WORDS * sizeof(unsigned);   // 39.3 MB each
    size_t need = keys_bytes + 2 * priv_bytes;                             // ~145.7 MB

    bool shape_ok = (n_events % NBLOCKS == 0) &&
                    (per_slice % (4 * NTHREADS) == 0);

    if (ws_size >= need && shape_ok) {
        uint4*    keys4 = (uint4*)d_ws;
        unsigned* priv0 = (unsigned*)((char*)d_ws + keys_bytes);
        unsigned* priv1 = (unsigned*)((char*)d_ws + keys_bytes + priv_bytes);

        // A: events read once -> ch0 hist + uint4 key stream (permuted order)
        hist_ch0_write_keys<<<NBLOCKS, NTHREADS, 0, stream>>>(
            events, priv0, keys4, per_slice);

        // B: ch1 hist from 4B keys
        hist_ch1_from_keys<<<NBLOCKS, NTHREADS, 0, stream>>>(
            keys4, priv1, per_slice);

        // C: reduce 2x256 copies + base -> out
        reduce_all<<<(C_WORDS + 255) / 256, 256, 0, stream>>>(
            priv0, priv1, (const float4*)event_image, (float4*)out);
    } else {
        // fallback: round-2 path (known-correct)
        int n_out = out_size;
        zero_kernel<<<(n_out + 255) / 256, 256, 0, stream>>>((unsigned*)out, n_out);
        event_scatter_fallback<<<2048, 256, 0, stream>>>(events, (unsigned*)out, n_events);
        finalize_fallback<<<(n_out + 255) / 256, 256, 0, stream>>>(event_image, out, n_out);
    }
}

// Round 11
// 110.969 us; speedup vs baseline: 1.5269x; 1.4607x over previous
//
#include <hip/hip_runtime.h>

#define SENSOR_W 640
#define SENSOR_H 480
#define HW_PIX (SENSOR_W * SENSOR_H)
#define N_OUT (2 * HW_PIX)                 // 614400 bins
#define RANGES 2
#define SLICES 128
#define BINS_PER_RANGE (N_OUT / RANGES)    // 307200 nibble bins per range
#define LDS_WORDS (BINS_PER_RANGE / 8)     // 38400 uint32 = 153,600 B LDS
#define OUT_WORDS (N_OUT / 8)              // 76800 packed words total
#define UNROLL 8

__device__ __forceinline__ unsigned make_key(float4 e) {
    int x = (int)e.x;                      // astype(int32) == trunc
    int y = (int)e.y;
    if (x >= 0 && x < SENSOR_W && y >= 0 && y < SENSOR_H) {
        unsigned ch = (e.w > 0.0f) ? 0u : 1u;    // pos -> ch0, neg -> ch1
        return ch * (unsigned)HW_PIX + (unsigned)y * SENSOR_W + (unsigned)x;
    }
    return 0xFFFFFFFFu;                    // falls in no range
}

// Round-6 structure (best so far: 110.7 us) with one change: 8-deep load
// unroll. 1 block/CU (153.6 KB LDS) = 4 waves/SIMD, so latency hiding must
// come from ILP — 8 outstanding 16B loads per wave instead of 4.
__global__ __launch_bounds__(1024)
void hist_fused(const float4* __restrict__ events,
                unsigned* __restrict__ priv32, int n_events) {
    __shared__ unsigned lds[LDS_WORDS];    // 307,200 4-bit counters
    int r = blockIdx.x / SLICES;           // 0..1   bin range
    int s = blockIdx.x % SLICES;           // 0..127 event slice

    for (int i = threadIdx.x; i < LDS_WORDS; i += 1024) lds[i] = 0u;
    __syncthreads();

    int per_slice = n_events / SLICES;     // 131072
    const float4* ev = events + (size_t)s * per_slice;
    unsigned rbase = (unsigned)r * BINS_PER_RANGE;

    int iters = per_slice / (UNROLL * 1024);   // 16
    for (int j = 0; j < iters; ++j) {
        int i = j * UNROLL * 1024 + threadIdx.x;
        float4 e[UNROLL];
        #pragma unroll
        for (int k = 0; k < UNROLL; ++k) e[k] = ev[i + k * 1024];
        #pragma unroll
        for (int k = 0; k < UNROLL; ++k) {
            unsigned l = make_key(e[k]) - rbase;
            if (l < BINS_PER_RANGE)
                atomicAdd(&lds[l >> 3], 1u << ((l & 7u) << 2));
        }
    }
    __syncthreads();

    // flush: region (r,s) owned by exactly this block -> plain coalesced stores
    unsigned* dst = priv32 + (size_t)blockIdx.x * LDS_WORDS;
    for (int i = threadIdx.x; i < LDS_WORDS; i += 1024) dst[i] = lds[i];
}

// Sum the 128 nibble-packed copies per range + base image -> float output.
// Byte-packed partial sums over 16-slice chunks (max 16*15 = 240 <= 255).
__global__ void reduce_fused(const unsigned* __restrict__ priv32,
                             const float4* __restrict__ base4,
                             float4* __restrict__ out4) {
    int w = blockIdx.x * blockDim.x + threadIdx.x;   // packed-word index
    if (w >= OUT_WORDS) return;
    int r = w / LDS_WORDS;                 // 0 or 1
    int lw = w - r * LDS_WORDS;
    const unsigned* src = priv32 + (size_t)r * SLICES * LDS_WORDS + lw;

    unsigned s0=0,s1=0,s2=0,s3=0,s4=0,s5=0,s6=0,s7=0;
    for (int c0 = 0; c0 < SLICES; c0 += 16) {
        unsigned alo = 0, ahi = 0;
        #pragma unroll
        for (int c = 0; c < 16; ++c) {
            unsigned v = src[(size_t)(c0 + c) * LDS_WORDS];
            alo += v & 0x0F0F0F0Fu;          // even nibbles -> bytes
            ahi += (v >> 4) & 0x0F0F0F0Fu;   // odd nibbles  -> bytes
        }
        s0 += alo & 0xFFu;  s2 += (alo >> 8) & 0xFFu;
        s4 += (alo >> 16) & 0xFFu;  s6 += alo >> 24;
        s1 += ahi & 0xFFu;  s3 += (ahi >> 8) & 0xFFu;
        s5 += (ahi >> 16) & 0xFFu;  s7 += ahi >> 24;
    }
    // word w covers global bins 8w..8w+7
    float4 b0 = base4[2 * w], b1 = base4[2 * w + 1];
    out4[2 * w]     = make_float4(b0.x + (float)s0, b0.y + (float)s1,
                                  b0.z + (float)s2, b0.w + (float)s3);
    out4[2 * w + 1] = make_float4(b1.x + (float)s4, b1.y + (float)s5,
                                  b1.z + (float)s6, b1.w + (float)s7);
}

// ---------- fallback (round-2 path: device atomics into d_out) ----------

__global__ void zero_kernel(unsigned* __restrict__ cnt, int n) {
    int i = blockIdx.x * blockDim.x + threadIdx.x;
    int stride = gridDim.x * blockDim.x;
    for (; i < n; i += stride) cnt[i] = 0u;
}

__global__ void event_scatter_fallback(const float4* __restrict__ events,
                                       unsigned* __restrict__ cnt, int n_events) {
    int i = blockIdx.x * blockDim.x + threadIdx.x;
    int stride = gridDim.x * blockDim.x;
    for (; i < n_events; i += stride) {
        float4 ev = events[i];
        int x = (int)ev.x, y = (int)ev.y;
        if (x >= 0 && x < SENSOR_W && y >= 0 && y < SENSOR_H) {
            int ch = (ev.w > 0.0f) ? 0 : 1;
            atomicAdd(&cnt[ch * HW_PIX + y * SENSOR_W + x], 1u);
        }
    }
}

__global__ void finalize_fallback(const float* __restrict__ event_image,
                                  float* __restrict__ out, int n) {
    int i = blockIdx.x * blockDim.x + threadIdx.x;
    int stride = gridDim.x * blockDim.x;
    for (; i < n; i += stride) {
        unsigned c = ((const unsigned*)out)[i];
        out[i] = event_image[i] + (float)c;
    }
}

extern "C" void kernel_launch(void* const* d_in, const int* in_sizes, int n_in,
                              void* d_out, int out_size, void* d_ws, size_t ws_size,
                              hipStream_t stream) {
    const float4* events = (const float4*)d_in[0];
    const float* event_image = (const float*)d_in[1];
    float* out = (float*)d_out;

    int n_events = in_sizes[0] / 4;                   // 16,777,216
    size_t priv_bytes = (size_t)RANGES * SLICES * LDS_WORDS * sizeof(unsigned); // 39.3 MB

    bool shape_ok = (n_events % SLICES == 0) &&
                    ((n_events / SLICES) % (UNROLL * 1024) == 0);

    if (ws_size >= priv_bytes && shape_ok) {
        unsigned* priv32 = (unsigned*)d_ws;

        // 1) fused decode+histogram (every priv word overwritten -> no memset)
        hist_fused<<<RANGES * SLICES, 1024, 0, stream>>>(events, priv32, n_events);

        // 2) reduce 128 nibble copies per range + base -> out
        reduce_fused<<<(OUT_WORDS + 255) / 256, 256, 0, stream>>>(
            priv32, (const float4*)event_image, (float4*)out);
    } else {
        // fallback: round-2 path (known-correct)
        int n_out = out_size;
        zero_kernel<<<(n_out + 255) / 256, 256, 0, stream>>>((unsigned*)out, n_out);
        event_scatter_fallback<<<2048, 256, 0, stream>>>(events, (unsigned*)out, n_events);
        finalize_fallback<<<(n_out + 255) / 256, 256, 0, stream>>>(event_image, out, n_out);
    }
}